// Round 1
// baseline (252.859 us; speedup 1.0000x reference)
//
#include <hip/hip_runtime.h>

#define HH 128
#define WW 256
#define DDEP 24

// ---------------- kernel A: tot (32x64) + uv output (2x32x64) ----------------
__global__ __launch_bounds__(256) void k_tot_uv(
    const float* __restrict__ sp, const float* __restrict__ xy,
    float* __restrict__ tot, float* __restrict__ uv_out)
{
  int cell = blockIdx.x * 256 + threadIdx.x;   // 0..2047
  int Y = cell >> 6, X = cell & 63;
  float tsum = 0.f, u0 = 0.f, u1 = 0.f;
  for (int iy = 0; iy < 4; ++iy) {
    int y = Y * 4 + iy;
    for (int ix = 0; ix < 4; ++ix) {
      int x = X * 4 + ix;
      float psum = 0.f;
#pragma unroll
      for (int k = 0; k < 9; ++k) {
        int oy = 4 * ((k / 3) - 1), ox = 4 * ((k % 3) - 1);
        int sy = y - oy, sx = x - ox;
        if (sy >= 0 && sy < HH && sx >= 0 && sx < WW)
          psum += sp[k * HH * WW + sy * WW + sx];
      }
      tsum += psum;
      // last-write-wins winner k*: largest k with valid mask
      int oy = (y >= 4) ? 4 : 0;
      int ox = (x >= 4) ? 4 : 0;
      int kk = (oy ? 2 : 1) * 3 + (ox ? 2 : 1);
      int sy = y - oy, sx = x - ox;
      float p = sp[kk * HH * WW + sy * WW + sx];
      u0 += xy[sy * WW + sx] * p;
      u1 += xy[HH * WW + sy * WW + sx] * p;
    }
  }
  float t = tsum * (1.f / 16.f);
  tot[cell] = t;
  float inv = 1.f / t;
  uv_out[cell] = u0 * (1.f / 16.f) * inv;
  uv_out[2048 + cell] = u1 * (1.f / 16.f) * inv;
}

// ------------- kernel B: fused shift/gather + normalize + stem conv ----------
// out: NDHWC [24][128][256][16]
__global__ __launch_bounds__(256) void k_stem(
    const float* __restrict__ cv, const float* __restrict__ sp,
    const float* __restrict__ wstem, const float* __restrict__ tot,
    float* __restrict__ out)
{
  __shared__ float wl[16 * 72];
  for (int i = threadIdx.x; i < 16 * 72; i += 256) wl[i] = wstem[i];
  __syncthreads();
  int x = blockIdx.x * 64 + (threadIdx.x & 63);
  int y = blockIdx.y * 4 + (threadIdx.x >> 6);
  int d = blockIdx.z;
  float acc[16];
#pragma unroll
  for (int o = 0; o < 16; ++o) acc[o] = 0.f;
#pragma unroll
  for (int k = 0; k < 9; ++k) {
    int oy = 4 * ((k / 3) - 1), ox = 4 * ((k % 3) - 1);
    int sy = y - oy, sx = x - ox;
    if (sy < 0 || sy >= HH || sx < 0 || sx >= WW) continue;
    float p = sp[k * HH * WW + sy * WW + sx];
    const float* cvp = cv + (size_t)d * HH * WW + sy * WW + sx;
#pragma unroll
    for (int ci = 0; ci < 8; ++ci) {
      float v = cvp[(size_t)ci * DDEP * HH * WW] * p;
#pragma unroll
      for (int o = 0; o < 16; ++o)
        acc[o] += wl[o * 72 + ci * 9 + k] * v;
    }
  }
  float inv = 1.f / tot[(y >> 2) * 64 + (x >> 2)];
  float* op = out + (((size_t)d * HH + y) * WW + x) * 16;
#pragma unroll
  for (int o = 0; o < 16; ++o) {
    float v = acc[o] * inv;
    op[o] = v > 0.f ? v : 0.f;
  }
}

// ------- kernel C: conv1a (32,16,3,2,2) stride(2,2,2) pad(1,0,0) + relu ------
// in NDHWC [24][128][256][16] -> out NDHWC [12][64][128][32]
__global__ __launch_bounds__(256) void k_conv1a(
    const float* __restrict__ in, const float* __restrict__ w,
    float* __restrict__ out)
{
  __shared__ float wl[6144];   // [(kd*2+ky)*2+kx][ci][o]
  for (int t = threadIdx.x; t < 6144; t += 256) {
    int o = t & 31, rest = t >> 5;
    int ci = rest & 15, pos = rest >> 4;
    int kx = pos & 1, ky = (pos >> 1) & 1, kd = pos >> 2;
    wl[t] = w[(((o * 16 + ci) * 3 + kd) * 2 + ky) * 2 + kx];
  }
  __syncthreads();
  int pid = blockIdx.x * 256 + threadIdx.x;   // 0..98303
  int xo = pid & 127, yo = (pid >> 7) & 63, dz = pid >> 13;
  float acc[32];
#pragma unroll
  for (int o = 0; o < 32; ++o) acc[o] = 0.f;
  for (int kd = 0; kd < 3; ++kd) {
    int d = 2 * dz - 1 + kd;
    if (d < 0 || d >= 24) continue;
#pragma unroll
    for (int ky = 0; ky < 2; ++ky)
#pragma unroll
      for (int kx = 0; kx < 2; ++kx) {
        int y = 2 * yo + ky, x = 2 * xo + kx;
        const float4* ip = (const float4*)(in + (((size_t)d * 128 + y) * 256 + x) * 16);
        float4 v0 = ip[0], v1 = ip[1], v2 = ip[2], v3 = ip[3];
        float iv[16] = {v0.x, v0.y, v0.z, v0.w, v1.x, v1.y, v1.z, v1.w,
                        v2.x, v2.y, v2.z, v2.w, v3.x, v3.y, v3.z, v3.w};
        const float* wp = &wl[((kd * 2 + ky) * 2 + kx) * 512];
#pragma unroll
        for (int ci = 0; ci < 16; ++ci)
#pragma unroll
          for (int o = 0; o < 32; ++o)
            acc[o] += wp[ci * 32 + o] * iv[ci];
      }
  }
  float* op = out + (((size_t)dz * 64 + yo) * 128 + xo) * 32;
#pragma unroll
  for (int o = 0; o < 32; ++o)
    op[o] = acc[o] > 0.f ? acc[o] : 0.f;
}

// --------- kernel D: conv1b (32,32,3,1,1) pad(1,0,0) + relu ------------------
// in NDHWC [12][64][128][32] -> outn NDHWC (ws) + outc NCDHW (d_out f1)
__global__ __launch_bounds__(256) void k_conv1b(
    const float* __restrict__ in, const float* __restrict__ w,
    float* __restrict__ outn, float* __restrict__ outc)
{
  __shared__ float wl[3072];   // [kd][ci][o]
  for (int t = threadIdx.x; t < 3072; t += 256) {
    int o = t & 31, ci = (t >> 5) & 31, kd = t >> 10;
    wl[t] = w[(o * 32 + ci) * 3 + kd];
  }
  __syncthreads();
  int pid = blockIdx.x * 256 + threadIdx.x;   // 0..98303
  int xo = pid & 127, yo = (pid >> 7) & 63, dz = pid >> 13;
  float acc[32];
#pragma unroll
  for (int o = 0; o < 32; ++o) acc[o] = 0.f;
  for (int kd = 0; kd < 3; ++kd) {
    int d = dz - 1 + kd;
    if (d < 0 || d >= 12) continue;
    const float4* ip = (const float4*)(in + (((size_t)d * 64 + yo) * 128 + xo) * 32);
    float iv[32];
#pragma unroll
    for (int q = 0; q < 8; ++q) {
      float4 v = ip[q];
      iv[q * 4 + 0] = v.x; iv[q * 4 + 1] = v.y; iv[q * 4 + 2] = v.z; iv[q * 4 + 3] = v.w;
    }
    const float* wp = &wl[kd * 1024];
#pragma unroll
    for (int ci = 0; ci < 32; ++ci)
#pragma unroll
      for (int o = 0; o < 32; ++o)
        acc[o] += wp[ci * 32 + o] * iv[ci];
  }
  float* onp = outn + (((size_t)dz * 64 + yo) * 128 + xo) * 32;
#pragma unroll
  for (int o = 0; o < 32; ++o) {
    float v = acc[o] > 0.f ? acc[o] : 0.f;
    onp[o] = v;
    outc[((size_t)(o * 12 + dz) * 64 + yo) * 128 + xo] = v;
  }
}

// ------- kernel E: conv2a (64,32,3,2,2) stride(2,2,2) pad(1,0,0) + relu ------
// in NDHWC [12][64][128][32] -> out NDHWC [6][32][64][64]; blockIdx.y = o-half
__global__ __launch_bounds__(256) void k_conv2a(
    const float* __restrict__ in, const float* __restrict__ w,
    float* __restrict__ out)
{
  __shared__ float wl[12288];  // [(kd,ky,kx)][ci][o(32)]
  int ohalf = blockIdx.y;
  for (int t = threadIdx.x; t < 12288; t += 256) {
    int o = t & 31, rest = t >> 5;
    int ci = rest & 31, pos = rest >> 5;
    int kx = pos & 1, ky = (pos >> 1) & 1, kd = pos >> 2;
    wl[t] = w[((((ohalf * 32 + o) * 32 + ci) * 3 + kd) * 2 + ky) * 2 + kx];
  }
  __syncthreads();
  int pid = blockIdx.x * 256 + threadIdx.x;   // 0..12287
  int xo = pid & 63, yo = (pid >> 6) & 31, dz = pid >> 11;
  float acc[32];
#pragma unroll
  for (int o = 0; o < 32; ++o) acc[o] = 0.f;
  for (int kd = 0; kd < 3; ++kd) {
    int d = 2 * dz - 1 + kd;
    if (d < 0 || d >= 12) continue;
#pragma unroll
    for (int ky = 0; ky < 2; ++ky)
#pragma unroll
      for (int kx = 0; kx < 2; ++kx) {
        int y = 2 * yo + ky, x = 2 * xo + kx;
        const float4* ip = (const float4*)(in + (((size_t)d * 64 + y) * 128 + x) * 32);
        float iv[32];
#pragma unroll
        for (int q = 0; q < 8; ++q) {
          float4 v = ip[q];
          iv[q * 4 + 0] = v.x; iv[q * 4 + 1] = v.y; iv[q * 4 + 2] = v.z; iv[q * 4 + 3] = v.w;
        }
        const float* wp = &wl[((kd * 2 + ky) * 2 + kx) * 1024];
#pragma unroll
        for (int ci = 0; ci < 32; ++ci)
#pragma unroll
          for (int o = 0; o < 32; ++o)
            acc[o] += wp[ci * 32 + o] * iv[ci];
      }
  }
  float* op = out + (((size_t)dz * 32 + yo) * 64 + xo) * 64 + ohalf * 32;
#pragma unroll
  for (int o = 0; o < 32; ++o)
    op[o] = acc[o] > 0.f ? acc[o] : 0.f;
}

// --------- kernel F: conv2b (64,64,3,1,1) pad(1,0,0) + relu ------------------
// in NDHWC [6][32][64][64] -> d_out f2 NCDHW (64,6,32,64); blockIdx.y = o-half
__global__ __launch_bounds__(256) void k_conv2b(
    const float* __restrict__ in, const float* __restrict__ w,
    float* __restrict__ out)
{
  __shared__ float wl[6144];   // [kd][ci(64)][o(32)]
  int ohalf = blockIdx.y;
  for (int t = threadIdx.x; t < 6144; t += 256) {
    int o = t & 31, ci = (t >> 5) & 63, kd = t >> 11;
    wl[t] = w[((ohalf * 32 + o) * 64 + ci) * 3 + kd];
  }
  __syncthreads();
  int pid = blockIdx.x * 256 + threadIdx.x;   // 0..12287
  int xo = pid & 63, yo = (pid >> 6) & 31, dz = pid >> 11;
  float acc[32];
#pragma unroll
  for (int o = 0; o < 32; ++o) acc[o] = 0.f;
  for (int kd = 0; kd < 3; ++kd) {
    int d = dz - 1 + kd;
    if (d < 0 || d >= 6) continue;
    const float4* ip = (const float4*)(in + (((size_t)d * 32 + yo) * 64 + xo) * 64);
    float iv[64];
#pragma unroll
    for (int q = 0; q < 16; ++q) {
      float4 v = ip[q];
      iv[q * 4 + 0] = v.x; iv[q * 4 + 1] = v.y; iv[q * 4 + 2] = v.z; iv[q * 4 + 3] = v.w;
    }
    const float* wp = &wl[kd * 2048];
#pragma unroll
    for (int ci = 0; ci < 64; ++ci)
#pragma unroll
      for (int o = 0; o < 32; ++o)
        acc[o] += wp[ci * 32 + o] * iv[ci];
  }
#pragma unroll
  for (int o = 0; o < 32; ++o) {
    float v = acc[o] > 0.f ? acc[o] : 0.f;
    out[((size_t)((ohalf * 32 + o) * 6 + dz) * 32 + yo) * 64 + xo] = v;
  }
}

extern "C" void kernel_launch(void* const* d_in, const int* in_sizes, int n_in,
                              void* d_out, int out_size, void* d_ws, size_t ws_size,
                              hipStream_t stream) {
  const float* cv    = (const float*)d_in[0];  // (1,8,24,128,256)
  const float* sp    = (const float*)d_in[1];  // (1,9,128,256)
  const float* xy    = (const float*)d_in[2];  // (1,2,128,256)
  const float* wstem = (const float*)d_in[3];  // (16,72,1,1,1)
  const float* w1a   = (const float*)d_in[4];  // (32,16,3,2,2)
  const float* w1b   = (const float*)d_in[5];  // (32,32,3,1,1)
  const float* w2a   = (const float*)d_in[6];  // (64,32,3,2,2)
  const float* w2b   = (const float*)d_in[7];  // (64,64,3,1,1)
  float* out = (float*)d_out;
  // output chunks: f1 (32*12*64*128=3145728) | f2 (64*6*32*64=786432) | uv (4096)
  float* out_f1 = out;
  float* out_f2 = out + 3145728;
  float* out_uv = out + 3145728 + 786432;

  float* ws = (float*)d_ws;
  float* t_tot  = ws;                       // 2048
  float* t_stem = ws + 2048;                // 24*128*256*16 = 12582912
  float* t_f1a  = t_stem + 12582912;        // 12*64*128*32 = 3145728
  float* t_f1n  = t_f1a + 3145728;          // 3145728
  float* t_f2a  = t_f1n + 3145728;          // 6*32*64*64 = 786432

  k_tot_uv<<<8, 256, 0, stream>>>(sp, xy, t_tot, out_uv);
  k_stem<<<dim3(4, 32, 24), 256, 0, stream>>>(cv, sp, wstem, t_tot, t_stem);
  k_conv1a<<<384, 256, 0, stream>>>(t_stem, w1a, t_f1a);
  k_conv1b<<<384, 256, 0, stream>>>(t_f1a, w1b, t_f1n, out_f1);
  k_conv2a<<<dim3(48, 2), 256, 0, stream>>>(t_f1n, w2a, t_f2a);
  k_conv2b<<<dim3(48, 2), 256, 0, stream>>>(t_f2a, w2b, out_f2);
}

// Round 2
// 196.613 us; speedup vs baseline: 1.2861x; 1.2861x over previous
//
#include <hip/hip_runtime.h>

#define HH 128
#define WW 256
#define DDEP 24

// ---------------- kernel A: tot (32x64) + uv output (2x32x64) ----------------
__global__ __launch_bounds__(256) void k_tot_uv(
    const float* __restrict__ sp, const float* __restrict__ xy,
    float* __restrict__ tot, float* __restrict__ uv_out)
{
  int cell = blockIdx.x * 256 + threadIdx.x;   // 0..2047
  int Y = cell >> 6, X = cell & 63;
  float tsum = 0.f, u0 = 0.f, u1 = 0.f;
  for (int iy = 0; iy < 4; ++iy) {
    int y = Y * 4 + iy;
    for (int ix = 0; ix < 4; ++ix) {
      int x = X * 4 + ix;
      float psum = 0.f;
#pragma unroll
      for (int k = 0; k < 9; ++k) {
        int oy = 4 * ((k / 3) - 1), ox = 4 * ((k % 3) - 1);
        int sy = y - oy, sx = x - ox;
        if (sy >= 0 && sy < HH && sx >= 0 && sx < WW)
          psum += sp[k * HH * WW + sy * WW + sx];
      }
      tsum += psum;
      int oy = (y >= 4) ? 4 : 0;
      int ox = (x >= 4) ? 4 : 0;
      int kk = (oy ? 2 : 1) * 3 + (ox ? 2 : 1);
      int sy = y - oy, sx = x - ox;
      float p = sp[kk * HH * WW + sy * WW + sx];
      u0 += xy[sy * WW + sx] * p;
      u1 += xy[HH * WW + sy * WW + sx] * p;
    }
  }
  float t = tsum * (1.f / 16.f);
  tot[cell] = t;
  float inv = 1.f / t;
  uv_out[cell] = u0 * (1.f / 16.f) * inv;
  uv_out[2048 + cell] = u1 * (1.f / 16.f) * inv;
}

// ------------- kernel B: fused shift/gather + normalize + stem conv ----------
// 4 x-pixels per thread (float4). out: NDHWC [24][128][256][16]
__global__ __launch_bounds__(256) void k_stem(
    const float* __restrict__ cv, const float* __restrict__ sp,
    const float* __restrict__ wstem, const float* __restrict__ tot,
    float* __restrict__ out)
{
  __shared__ float wl[1152];   // [k][ci][o]
  for (int i = threadIdx.x; i < 1152; i += 256) {
    int o = i & 15, ci = (i >> 4) & 7, k = i >> 7;
    wl[i] = wstem[o * 72 + ci * 9 + k];
  }
  __syncthreads();
  int x0 = 4 * (threadIdx.x & 63);
  int y = blockIdx.x * 4 + (threadIdx.x >> 6);
  int d = blockIdx.y;
  float acc[16][4];
#pragma unroll
  for (int o = 0; o < 16; ++o)
#pragma unroll
    for (int p = 0; p < 4; ++p) acc[o][p] = 0.f;
#pragma unroll
  for (int k = 0; k < 9; ++k) {
    int oy = 4 * ((k / 3) - 1), ox = 4 * ((k % 3) - 1);
    int sy = y - oy, sx0 = x0 - ox;
    if (sy < 0 || sy >= HH || sx0 < 0 || sx0 >= WW) continue;
    float4 p4 = *(const float4*)(sp + k * HH * WW + sy * WW + sx0);
#pragma unroll
    for (int ci = 0; ci < 8; ++ci) {
      float4 c4 = *(const float4*)(cv + (((size_t)(ci * 24 + d)) * HH + sy) * WW + sx0);
      float t0 = c4.x * p4.x, t1 = c4.y * p4.y, t2 = c4.z * p4.z, t3 = c4.w * p4.w;
      const float* wb = &wl[(k * 8 + ci) * 16];
      float wv[16];
#pragma unroll
      for (int q = 0; q < 4; ++q) *(float4*)&wv[q * 4] = *(const float4*)(wb + q * 4);
#pragma unroll
      for (int o = 0; o < 16; ++o) {
        acc[o][0] += wv[o] * t0;
        acc[o][1] += wv[o] * t1;
        acc[o][2] += wv[o] * t2;
        acc[o][3] += wv[o] * t3;
      }
    }
  }
  float inv = 1.f / tot[(y >> 2) * 64 + (x0 >> 2)];
  float* op = out + (((size_t)d * HH + y) * WW + x0) * 16;
#pragma unroll
  for (int p = 0; p < 4; ++p)
#pragma unroll
    for (int q = 0; q < 4; ++q) {
      float4 v;
      v.x = fmaxf(acc[q * 4 + 0][p] * inv, 0.f);
      v.y = fmaxf(acc[q * 4 + 1][p] * inv, 0.f);
      v.z = fmaxf(acc[q * 4 + 2][p] * inv, 0.f);
      v.w = fmaxf(acc[q * 4 + 3][p] * inv, 0.f);
      *(float4*)(op + p * 16 + q * 4) = v;
    }
}

// ------- kernel C: conv1a (32,16,3,2,2) s(2,2,2) p(1,0,0) + relu -------------
// 4px x 16o per thread. in NDHWC [24][128][256][16] -> out NDHWC [12][64][128][32]
__global__ __launch_bounds__(256) void k_conv1a(
    const float* __restrict__ in, const float* __restrict__ w,
    float* __restrict__ out)
{
  __shared__ float wl[3072];   // [pos][ci][o16]
  int oh = blockIdx.z;
  for (int i = threadIdx.x; i < 3072; i += 256) {
    int o = i & 15, ci = (i >> 4) & 15, pos = i >> 8;
    int kx = pos & 1, ky = (pos >> 1) & 1, kd = pos >> 2;
    wl[i] = w[(((oh * 16 + o) * 16 + ci) * 3 + kd) * 4 + ky * 2 + kx];
  }
  __syncthreads();
  int xo0 = 4 * (threadIdx.x & 31);
  int yo = blockIdx.x * 8 + (threadIdx.x >> 5);
  int dz = blockIdx.y;
  float acc[16][4];
#pragma unroll
  for (int o = 0; o < 16; ++o)
#pragma unroll
    for (int p = 0; p < 4; ++p) acc[o][p] = 0.f;
#pragma unroll
  for (int kd = 0; kd < 3; ++kd) {
    int d = 2 * dz - 1 + kd;
    if (d < 0 || d >= 24) continue;
#pragma unroll
    for (int ky = 0; ky < 2; ++ky) {
      int y = 2 * yo + ky;
#pragma unroll
      for (int kx = 0; kx < 2; ++kx) {
        float iv[16][4];
#pragma unroll
        for (int p = 0; p < 4; ++p) {
          const float4* ip = (const float4*)(in + (((size_t)d * 128 + y) * 256 + (2 * (xo0 + p) + kx)) * 16);
#pragma unroll
          for (int q = 0; q < 4; ++q) {
            float4 v = ip[q];
            iv[q * 4 + 0][p] = v.x; iv[q * 4 + 1][p] = v.y;
            iv[q * 4 + 2][p] = v.z; iv[q * 4 + 3][p] = v.w;
          }
        }
        const float* wbase = &wl[((kd * 2 + ky) * 2 + kx) * 256];
#pragma unroll
        for (int ci = 0; ci < 16; ++ci) {
          float wv[16];
#pragma unroll
          for (int q = 0; q < 4; ++q) *(float4*)&wv[q * 4] = *(const float4*)(wbase + ci * 16 + q * 4);
#pragma unroll
          for (int o = 0; o < 16; ++o) {
            acc[o][0] += wv[o] * iv[ci][0];
            acc[o][1] += wv[o] * iv[ci][1];
            acc[o][2] += wv[o] * iv[ci][2];
            acc[o][3] += wv[o] * iv[ci][3];
          }
        }
      }
    }
  }
  float* op = out + (((size_t)dz * 64 + yo) * 128 + xo0) * 32 + oh * 16;
#pragma unroll
  for (int p = 0; p < 4; ++p)
#pragma unroll
    for (int q = 0; q < 4; ++q) {
      float4 v;
      v.x = fmaxf(acc[q * 4 + 0][p], 0.f);
      v.y = fmaxf(acc[q * 4 + 1][p], 0.f);
      v.z = fmaxf(acc[q * 4 + 2][p], 0.f);
      v.w = fmaxf(acc[q * 4 + 3][p], 0.f);
      *(float4*)(op + p * 32 + q * 4) = v;
    }
}

// --------- kernel D: conv1b (32,32,3,1,1) p(1,0,0) + relu --------------------
// 2px x 16o per thread. in NDHWC -> outn NDHWC (ws) + outc NCDHW (d_out f1)
__global__ __launch_bounds__(256) void k_conv1b(
    const float* __restrict__ in, const float* __restrict__ w,
    float* __restrict__ outn, float* __restrict__ outc)
{
  __shared__ float wl[1536];   // [kd][ci][o16]
  int oh = blockIdx.z;
  for (int i = threadIdx.x; i < 1536; i += 256) {
    int o = i & 15, ci = (i >> 4) & 31, kd = i >> 9;
    wl[i] = w[((oh * 16 + o) * 32 + ci) * 3 + kd];
  }
  __syncthreads();
  int xo0 = 2 * (threadIdx.x & 63);
  int yo = blockIdx.x * 4 + (threadIdx.x >> 6);
  int dz = blockIdx.y;
  float acc[16][2];
#pragma unroll
  for (int o = 0; o < 16; ++o) { acc[o][0] = 0.f; acc[o][1] = 0.f; }
#pragma unroll
  for (int kd = 0; kd < 3; ++kd) {
    int d = dz - 1 + kd;
    if (d < 0 || d >= 12) continue;
    float iv[32][2];
#pragma unroll
    for (int p = 0; p < 2; ++p) {
      const float4* ip = (const float4*)(in + (((size_t)d * 64 + yo) * 128 + xo0 + p) * 32);
#pragma unroll
      for (int q = 0; q < 8; ++q) {
        float4 v = ip[q];
        iv[q * 4 + 0][p] = v.x; iv[q * 4 + 1][p] = v.y;
        iv[q * 4 + 2][p] = v.z; iv[q * 4 + 3][p] = v.w;
      }
    }
    const float* wbase = &wl[kd * 512];
#pragma unroll
    for (int ci = 0; ci < 32; ++ci) {
      float wv[16];
#pragma unroll
      for (int q = 0; q < 4; ++q) *(float4*)&wv[q * 4] = *(const float4*)(wbase + ci * 16 + q * 4);
#pragma unroll
      for (int o = 0; o < 16; ++o) {
        acc[o][0] += wv[o] * iv[ci][0];
        acc[o][1] += wv[o] * iv[ci][1];
      }
    }
  }
  float* onp = outn + (((size_t)dz * 64 + yo) * 128 + xo0) * 32 + oh * 16;
#pragma unroll
  for (int p = 0; p < 2; ++p)
#pragma unroll
    for (int q = 0; q < 4; ++q) {
      float4 v;
      v.x = fmaxf(acc[q * 4 + 0][p], 0.f);
      v.y = fmaxf(acc[q * 4 + 1][p], 0.f);
      v.z = fmaxf(acc[q * 4 + 2][p], 0.f);
      v.w = fmaxf(acc[q * 4 + 3][p], 0.f);
      *(float4*)(onp + p * 32 + q * 4) = v;
    }
#pragma unroll
  for (int o = 0; o < 16; ++o)
#pragma unroll
    for (int p = 0; p < 2; ++p)
      outc[(((size_t)(oh * 16 + o) * 12 + dz) * 64 + yo) * 128 + xo0 + p] = fmaxf(acc[o][p], 0.f);
}

// ------- kernel E: conv2a (64,32,3,2,2) s(2,2,2) p(1,0,0) + relu -------------
// 2px x 8o. in NDHWC [12][64][128][32] -> out NDHWC [6][32][64][64]
__global__ __launch_bounds__(256) void k_conv2a(
    const float* __restrict__ in, const float* __restrict__ w,
    float* __restrict__ out)
{
  __shared__ float wl[3072];   // [pos][ci32][o8]
  int og = blockIdx.z;
  for (int i = threadIdx.x; i < 3072; i += 256) {
    int o = i & 7, ci = (i >> 3) & 31, pos = i >> 8;
    int kx = pos & 1, ky = (pos >> 1) & 1, kd = pos >> 2;
    wl[i] = w[(((og * 8 + o) * 32 + ci) * 3 + kd) * 4 + ky * 2 + kx];
  }
  __syncthreads();
  int xo0 = 2 * (threadIdx.x & 31);
  int yo = blockIdx.x * 8 + (threadIdx.x >> 5);
  int dz = blockIdx.y;
  float acc[8][2];
#pragma unroll
  for (int o = 0; o < 8; ++o) { acc[o][0] = 0.f; acc[o][1] = 0.f; }
#pragma unroll
  for (int kd = 0; kd < 3; ++kd) {
    int d = 2 * dz - 1 + kd;
    if (d < 0 || d >= 12) continue;
#pragma unroll
    for (int ky = 0; ky < 2; ++ky) {
      int y = 2 * yo + ky;
#pragma unroll
      for (int kx = 0; kx < 2; ++kx) {
        float iv[32][2];
#pragma unroll
        for (int p = 0; p < 2; ++p) {
          const float4* ip = (const float4*)(in + (((size_t)d * 64 + y) * 128 + (2 * (xo0 + p) + kx)) * 32);
#pragma unroll
          for (int q = 0; q < 8; ++q) {
            float4 v = ip[q];
            iv[q * 4 + 0][p] = v.x; iv[q * 4 + 1][p] = v.y;
            iv[q * 4 + 2][p] = v.z; iv[q * 4 + 3][p] = v.w;
          }
        }
        const float* wbase = &wl[((kd * 2 + ky) * 2 + kx) * 256];
#pragma unroll
        for (int ci = 0; ci < 32; ++ci) {
          float wv[8];
          *(float4*)&wv[0] = *(const float4*)(wbase + ci * 8);
          *(float4*)&wv[4] = *(const float4*)(wbase + ci * 8 + 4);
#pragma unroll
          for (int o = 0; o < 8; ++o) {
            acc[o][0] += wv[o] * iv[ci][0];
            acc[o][1] += wv[o] * iv[ci][1];
          }
        }
      }
    }
  }
  float* op = out + (((size_t)dz * 32 + yo) * 64 + xo0) * 64 + og * 8;
#pragma unroll
  for (int p = 0; p < 2; ++p)
#pragma unroll
    for (int q = 0; q < 2; ++q) {
      float4 v;
      v.x = fmaxf(acc[q * 4 + 0][p], 0.f);
      v.y = fmaxf(acc[q * 4 + 1][p], 0.f);
      v.z = fmaxf(acc[q * 4 + 2][p], 0.f);
      v.w = fmaxf(acc[q * 4 + 3][p], 0.f);
      *(float4*)(op + p * 64 + q * 4) = v;
    }
}

// --------- kernel F: conv2b (64,64,3,1,1) p(1,0,0) + relu --------------------
// 2px x 8o. in NDHWC [6][32][64][64] -> d_out f2 NCDHW (64,6,32,64)
__global__ __launch_bounds__(256) void k_conv2b(
    const float* __restrict__ in, const float* __restrict__ w,
    float* __restrict__ out)
{
  __shared__ float wl[1536];   // [kd][ci64][o8]
  int og = blockIdx.z;
  for (int i = threadIdx.x; i < 1536; i += 256) {
    int o = i & 7, ci = (i >> 3) & 63, kd = i >> 9;
    wl[i] = w[((og * 8 + o) * 64 + ci) * 3 + kd];
  }
  __syncthreads();
  int xo0 = 2 * (threadIdx.x & 31);
  int yo = blockIdx.x * 8 + (threadIdx.x >> 5);
  int dz = blockIdx.y;
  float acc[8][2];
#pragma unroll
  for (int o = 0; o < 8; ++o) { acc[o][0] = 0.f; acc[o][1] = 0.f; }
#pragma unroll
  for (int kd = 0; kd < 3; ++kd) {
    int d = dz - 1 + kd;
    if (d < 0 || d >= 6) continue;
#pragma unroll
    for (int half = 0; half < 2; ++half) {
      float iv[32][2];
#pragma unroll
      for (int p = 0; p < 2; ++p) {
        const float4* ip = (const float4*)(in + (((size_t)d * 32 + yo) * 64 + xo0 + p) * 64 + half * 32);
#pragma unroll
        for (int q = 0; q < 8; ++q) {
          float4 v = ip[q];
          iv[q * 4 + 0][p] = v.x; iv[q * 4 + 1][p] = v.y;
          iv[q * 4 + 2][p] = v.z; iv[q * 4 + 3][p] = v.w;
        }
      }
      const float* wbase = &wl[kd * 512 + half * 256];
#pragma unroll
      for (int ci = 0; ci < 32; ++ci) {
        float wv[8];
        *(float4*)&wv[0] = *(const float4*)(wbase + ci * 8);
        *(float4*)&wv[4] = *(const float4*)(wbase + ci * 8 + 4);
#pragma unroll
        for (int o = 0; o < 8; ++o) {
          acc[o][0] += wv[o] * iv[ci][0];
          acc[o][1] += wv[o] * iv[ci][1];
        }
      }
    }
  }
#pragma unroll
  for (int o = 0; o < 8; ++o)
#pragma unroll
    for (int p = 0; p < 2; ++p)
      out[(((size_t)(og * 8 + o) * 6 + dz) * 32 + yo) * 64 + xo0 + p] = fmaxf(acc[o][p], 0.f);
}

extern "C" void kernel_launch(void* const* d_in, const int* in_sizes, int n_in,
                              void* d_out, int out_size, void* d_ws, size_t ws_size,
                              hipStream_t stream) {
  const float* cv    = (const float*)d_in[0];
  const float* sp    = (const float*)d_in[1];
  const float* xy    = (const float*)d_in[2];
  const float* wstem = (const float*)d_in[3];
  const float* w1a   = (const float*)d_in[4];
  const float* w1b   = (const float*)d_in[5];
  const float* w2a   = (const float*)d_in[6];
  const float* w2b   = (const float*)d_in[7];
  float* out = (float*)d_out;
  float* out_f1 = out;
  float* out_f2 = out + 3145728;
  float* out_uv = out + 3145728 + 786432;

  float* ws = (float*)d_ws;
  float* t_tot  = ws;                       // 2048
  float* t_stem = ws + 2048;                // 24*128*256*16
  float* t_f1a  = t_stem + 12582912;        // 12*64*128*32
  float* t_f1n  = t_f1a + 3145728;
  float* t_f2a  = t_f1n + 3145728;          // 6*32*64*64

  k_tot_uv<<<8, 256, 0, stream>>>(sp, xy, t_tot, out_uv);
  k_stem<<<dim3(32, 24), 256, 0, stream>>>(cv, sp, wstem, t_tot, t_stem);
  k_conv1a<<<dim3(8, 12, 2), 256, 0, stream>>>(t_stem, w1a, t_f1a);
  k_conv1b<<<dim3(16, 12, 2), 256, 0, stream>>>(t_f1a, w1b, t_f1n, out_f1);
  k_conv2a<<<dim3(4, 6, 8), 256, 0, stream>>>(t_f1n, w2a, t_f2a);
  k_conv2b<<<dim3(4, 6, 8), 256, 0, stream>>>(t_f2a, w2b, out_f2);
}